// Round 4
// baseline (400.518 us; speedup 1.0000x reference)
//
#include <hip/hip_runtime.h>
#include <hip/hip_cooperative_groups.h>
#include <stdint.h>

namespace cg = cooperative_groups;

#define D_EMB   64
#define N_ROWS  4096
#define DIM     512
#define KNEG    64
#define P_PAIRS 62
#define BPE     16                      // chunks per embedding in phase 1
#define RPB     (N_ROWS / BPE)          // 256 rows per chunk
#define NCHUNK  (D_EMB * BPE)           // 1024 chunks
#define EPSN    1e-8f
#define INV_T   10.0f

// ---------------- threefry-2x32-20 (matches JAX partitionable path) ---------
__device__ __forceinline__ uint32_t rotl32(uint32_t v, uint32_t r) {
  return (v << r) | (v >> (32u - r));
}

__device__ __forceinline__ void threefry(uint32_t k0, uint32_t k1,
                                         uint32_t c0, uint32_t c1,
                                         uint32_t& o0, uint32_t& o1) {
  uint32_t ks0 = k0, ks1 = k1, ks2 = k0 ^ k1 ^ 0x1BD11BDAu;
  uint32_t x0 = c0 + ks0, x1 = c1 + ks1;
#define RG(a,b,c,d) \
  x0 += x1; x1 = rotl32(x1,a); x1 ^= x0; \
  x0 += x1; x1 = rotl32(x1,b); x1 ^= x0; \
  x0 += x1; x1 = rotl32(x1,c); x1 ^= x0; \
  x0 += x1; x1 = rotl32(x1,d); x1 ^= x0;
  RG(13,15,26,6)   x0 += ks1; x1 += ks2 + 1u;
  RG(17,29,16,24)  x0 += ks2; x1 += ks0 + 2u;
  RG(13,15,26,6)   x0 += ks0; x1 += ks1 + 3u;
  RG(17,29,16,24)  x0 += ks1; x1 += ks2 + 4u;
  RG(13,15,26,6)   x0 += ks2; x1 += ks0 + 5u;
#undef RG
  o0 = x0; o1 = x1;
}

// ---------------- shared-memory block (shared by both launch paths) ---------
struct Shm {
  float    lds[4 * DIM];      // 8 KB: phase-1 column transpose
  float    nlds[RPB];         // 1 KB
  float    rA[4], rB[4], rC[4];
  int      wbi[4];
  int      topidx[KNEG];
  uint32_t bits[126];
  uint32_t sk[2];
  int      sel[KNEG];
  float    simi[KNEG], simj[KNEG];
};

// ---------------- phase 1: one 256-row chunk -> partial sums + norms --------
__device__ void phase1(Shm& s, const float* __restrict__ I,
                       float* __restrict__ partial, float* __restrict__ norms,
                       int chunk, int t, int lane, int w) {
  const int e = chunk >> 4, b = chunk & 15;
  const float4* base = reinterpret_cast<const float4*>(I) + (size_t)e * N_ROWS * (DIM / 4);
  float acc[8] = {0.f,0.f,0.f,0.f,0.f,0.f,0.f,0.f};
  const int nbase = b * RPB;
  for (int i = 0; i < RPB / 4; ++i) {
    const int n = nbase + i * 4 + w;
    const float4* row = base + (size_t)n * (DIM / 4);
    float4 A = row[lane];
    float4 B = row[lane + 64];
    acc[0] += A.x; acc[1] += A.y; acc[2] += A.z; acc[3] += A.w;
    acc[4] += B.x; acc[5] += B.y; acc[6] += B.z; acc[7] += B.w;
    float sq = A.x*A.x + A.y*A.y + A.z*A.z + A.w*A.w
             + B.x*B.x + B.y*B.y + B.z*B.z + B.w*B.w;
#pragma unroll
    for (int off = 32; off; off >>= 1) sq += __shfl_xor(sq, off);
    if (lane == 0) s.nlds[i * 4 + w] = sqrtf(sq);
  }
  const int p0 = 4 * lane;
#pragma unroll
  for (int q = 0; q < 4; ++q) {
    s.lds[w * DIM + p0 + q]       = acc[q];
    s.lds[w * DIM + 256 + p0 + q] = acc[4 + q];
  }
  __syncthreads();
  float s0 = s.lds[t] + s.lds[DIM + t] + s.lds[2*DIM + t] + s.lds[3*DIM + t];
  float s1 = s.lds[256 + t] + s.lds[DIM + 256 + t] + s.lds[2*DIM + 256 + t] + s.lds[3*DIM + 256 + t];
  float* po = partial + (size_t)chunk * DIM;
  po[t] = s0;
  po[256 + t] = s1;
  norms[e * N_ROWS + nbase + t] = s.nlds[t];
  __syncthreads();                       // lds/nlds safe for next chunk
}

// ---------------- phase 2a: per-embedding top64 + fold + sumneg + norms -----
__device__ void phase2(Shm& s, const float* __restrict__ I,
                       const float* __restrict__ partial,
                       const float* __restrict__ norms,
                       float* __restrict__ samples, float* __restrict__ snorm,
                       int e, int t, int lane, int w) {
  float v[16];
#pragma unroll
  for (int q = 0; q < 16; ++q) v[q] = norms[e * N_ROWS + q * 256 + t];
  float lmax = v[0]; int lidx = t;
#pragma unroll
  for (int q = 1; q < 16; ++q)
    if (v[q] > lmax) { lmax = v[q]; lidx = q * 256 + t; }

  for (int k = 0; k < KNEG; ++k) {
    float bv = lmax; int bi = lidx;
#pragma unroll
    for (int off = 32; off; off >>= 1) {
      float ov = __shfl_xor(bv, off);
      int   oi = __shfl_xor(bi, off);
      if (ov > bv || (ov == bv && oi < bi)) { bv = ov; bi = oi; }
    }
    if (lane == 0) { s.rA[w] = bv; s.wbi[w] = bi; }
    __syncthreads();
    float fv = s.rA[0]; int fi = s.wbi[0];
#pragma unroll
    for (int q = 1; q < 4; ++q)
      if (s.rA[q] > fv || (s.rA[q] == fv && s.wbi[q] < fi)) { fv = s.rA[q]; fi = s.wbi[q]; }
    if (t == (fi & 255)) {               // owner removes & rescans its 16
      v[fi >> 8] = -1e30f;
      lmax = v[0]; lidx = t;
#pragma unroll
      for (int q = 1; q < 16; ++q)
        if (v[q] > lmax) { lmax = v[q]; lidx = q * 256 + t; }
    }
    if (t == 0) s.topidx[k] = fi;
    __syncthreads();
  }

  float s0 = 0.f, s1 = 0.f;
  for (int b2 = 0; b2 < BPE; ++b2) {
    const float* pp = partial + (size_t)(e * BPE + b2) * DIM;
    s0 += pp[t];
    s1 += pp[256 + t];
  }
  const float* base = I + (size_t)e * N_ROWS * DIM;
  float a0 = 0.f, a1 = 0.f;
#pragma unroll 4
  for (int k = 0; k < KNEG; ++k) {
    const float* r = base + (size_t)s.topidx[k] * DIM;
    a0 += r[t];
    a1 += r[256 + t];
  }
  float sn0 = s0 - a0, sn1 = s1 - a1;

  float q1 = s0 * s0 + s1 * s1, q2 = sn0 * sn0 + sn1 * sn1;
#pragma unroll
  for (int off = 32; off; off >>= 1) {
    q1 += __shfl_xor(q1, off);
    q2 += __shfl_xor(q2, off);
  }
  if (lane == 0) { s.rA[w] = q1; s.rB[w] = q2; }
  __syncthreads();
  if (t == 0) {
    float n1 = s.rA[0] + s.rA[1] + s.rA[2] + s.rA[3];
    float n2 = s.rB[0] + s.rB[1] + s.rB[2] + s.rB[3];
    snorm[e]         = fmaxf(sqrtf(n1), EPSN);
    snorm[D_EMB + e] = fmaxf(sqrtf(n2), EPSN);
  }
  samples[(size_t)e * DIM + t]                 = s0;
  samples[(size_t)e * DIM + 256 + t]           = s1;
  samples[(size_t)(D_EMB + e) * DIM + t]       = sn0;
  samples[(size_t)(D_EMB + e) * DIM + 256 + t] = sn1;
}

// ---------------- phase 2b: positive-pair scalar ----------------------------
__device__ void phase2pos(Shm& s, const float* __restrict__ g1,
                          const float* __restrict__ g2,
                          float* __restrict__ posp, int t, int lane, int w) {
  float x0 = g1[t], x1 = g1[256 + t], y0 = g2[t], y1 = g2[256 + t];
  float d = x0*y0 + x1*y1, sa = x0*x0 + x1*x1, sb = y0*y0 + y1*y1;
#pragma unroll
  for (int off = 32; off; off >>= 1) {
    d  += __shfl_xor(d, off);
    sa += __shfl_xor(sa, off);
    sb += __shfl_xor(sb, off);
  }
  if (lane == 0) { s.rA[w] = d; s.rB[w] = sa; s.rC[w] = sb; }
  __syncthreads();
  if (t == 0) {
    float dt = s.rA[0] + s.rA[1] + s.rA[2] + s.rA[3];
    float s1 = s.rB[0] + s.rB[1] + s.rB[2] + s.rB[3];
    float s2 = s.rC[0] + s.rC[1] + s.rC[2] + s.rC[3];
    posp[0] = dt / (fmaxf(sqrtf(s1), EPSN) * fmaxf(sqrtf(s2), EPSN)) * INV_T;
  }
}

// ---------------- phase 3: select + cosine sims + LSE + pair loss -----------
__device__ void phase3(Shm& s, const float* __restrict__ samples,
                       const float* __restrict__ snorm,
                       const float* __restrict__ posp,
                       float* __restrict__ pairloss, int p, int t, int lane, int w) {
  if (t == 0) {
    uint32_t kh, kl, a, b;
    threefry(0u, 42u, 0u, (uint32_t)p, kh, kl);   // keys[p] = split(key(42),62)[p]
    threefry(kh, kl, 0u, 1u, a, b);               // subkey = split(keys[p])[1]
    s.sk[0] = a; s.sk[1] = b;
  }
  __syncthreads();
  if (t < 126) {
    uint32_t a, b;
    threefry(s.sk[0], s.sk[1], 0u, (uint32_t)t, a, b);
    s.bits[t] = a ^ b;                            // partitionable 32-bit path
  }
  __syncthreads();
  if (t < 126) {
    const uint32_t myb = s.bits[t];
    int rank = 0;
    for (int j = 0; j < 126; ++j) {
      const uint32_t bj = s.bits[j];
      rank += ((bj < myb) || (bj == myb && j < t)) ? 1 : 0;
    }
    if (rank < KNEG) {
      int vv = t + (t >= p ? 1 : 0);              // cand mapping: skip i=p
      vv += (vv >= p + 2 ? 1 : 0);                // then skip j=p+2
      s.sel[rank] = vv;
    }
  }
  __syncthreads();

  const float4* S = reinterpret_cast<const float4*>(samples);
  const float4 siA = S[p * 128 + lane],       siB = S[p * 128 + 64 + lane];
  const float4 sjA = S[(p + 2) * 128 + lane], sjB = S[(p + 2) * 128 + 64 + lane];
  const float ni = snorm[p], nj = snorm[p + 2];
  for (int k = w; k < KNEG; k += 4) {
    const int r = s.sel[k];
    const float4 vA = S[r * 128 + lane], vB = S[r * 128 + 64 + lane];
    float di = siA.x*vA.x + siA.y*vA.y + siA.z*vA.z + siA.w*vA.w
             + siB.x*vB.x + siB.y*vB.y + siB.z*vB.z + siB.w*vB.w;
    float dj = sjA.x*vA.x + sjA.y*vA.y + sjA.z*vA.z + sjA.w*vA.w
             + sjB.x*vB.x + sjB.y*vB.y + sjB.z*vB.z + sjB.w*vB.w;
#pragma unroll
    for (int off = 32; off; off >>= 1) {
      di += __shfl_xor(di, off);
      dj += __shfl_xor(dj, off);
    }
    if (lane == 0) {
      const float nr = snorm[r];
      s.simi[k] = di / (ni * nr) * INV_T;
      s.simj[k] = dj / (nj * nr) * INV_T;
    }
  }
  __syncthreads();
  if (t < KNEG) {
    const float xi = s.simi[t], xj = s.simj[t];
    float mi = xi, mj = xj;
#pragma unroll
    for (int off = 32; off; off >>= 1) {
      mi = fmaxf(mi, __shfl_xor(mi, off));
      mj = fmaxf(mj, __shfl_xor(mj, off));
    }
    float ei = expf(xi - mi), ej = expf(xj - mj);
#pragma unroll
    for (int off = 32; off; off >>= 1) {
      ei += __shfl_xor(ei, off);
      ej += __shfl_xor(ej, off);
    }
    if (t == 0) {
      const float pos = posp[0];
      const float lsei = mi + logf(ei), lsej = mj + logf(ej);
      const float li = fmaxf(pos, lsei) + log1pf(expf(-fabsf(pos - lsei))) - pos;
      const float lj = fmaxf(pos, lsej) + log1pf(expf(-fabsf(pos - lsej))) - pos;
      pairloss[p] = li + lj;
    }
  }
}

// ---------------- phase 4: final scalar sum ---------------------------------
__device__ void phase4(const float* __restrict__ pairloss, float* __restrict__ out, int t) {
  if (t < 64) {
    float vv = (t < P_PAIRS) ? pairloss[t] : 0.f;
#pragma unroll
    for (int off = 32; off; off >>= 1) vv += __shfl_xor(vv, off);
    if (t == 0) out[0] = vv;
  }
}

// ---------------- cooperative single-kernel path ----------------------------
__global__ __launch_bounds__(256, 4) void k_all(const float* __restrict__ I,
                                                const float* __restrict__ g1,
                                                const float* __restrict__ g2,
                                                float* __restrict__ partial,
                                                float* __restrict__ norms,
                                                float* __restrict__ samples,
                                                float* __restrict__ snorm,
                                                float* __restrict__ posp,
                                                float* __restrict__ pairloss,
                                                float* __restrict__ out) {
  cg::grid_group grid = cg::this_grid();
  const int t = threadIdx.x, lane = t & 63, w = t >> 6;
  __shared__ Shm s;

  for (int c = blockIdx.x; c < NCHUNK; c += gridDim.x)
    phase1(s, I, partial, norms, c, t, lane, w);
  grid.sync();

  if (blockIdx.x < D_EMB)
    phase2(s, I, partial, norms, samples, snorm, blockIdx.x, t, lane, w);
  else if (blockIdx.x == D_EMB)
    phase2pos(s, g1, g2, posp, t, lane, w);
  grid.sync();

  if (blockIdx.x < P_PAIRS)
    phase3(s, samples, snorm, posp, pairloss, blockIdx.x, t, lane, w);
  grid.sync();

  if (blockIdx.x == 0)
    phase4(pairloss, out, t);
}

// ---------------- fallback 4-kernel path ------------------------------------
__global__ __launch_bounds__(256) void k_p1(const float* __restrict__ I,
                                            float* __restrict__ partial,
                                            float* __restrict__ norms) {
  __shared__ Shm s;
  const int t = threadIdx.x;
  phase1(s, I, partial, norms, blockIdx.x, t, t & 63, t >> 6);
}

__global__ __launch_bounds__(256) void k_p2(const float* __restrict__ I,
                                            const float* __restrict__ partial,
                                            const float* __restrict__ norms,
                                            const float* __restrict__ g1,
                                            const float* __restrict__ g2,
                                            float* __restrict__ samples,
                                            float* __restrict__ snorm,
                                            float* __restrict__ posp) {
  __shared__ Shm s;
  const int t = threadIdx.x;
  if (blockIdx.x < D_EMB)
    phase2(s, I, partial, norms, samples, snorm, blockIdx.x, t, t & 63, t >> 6);
  else
    phase2pos(s, g1, g2, posp, t, t & 63, t >> 6);
}

__global__ __launch_bounds__(256) void k_p3(const float* __restrict__ samples,
                                            const float* __restrict__ snorm,
                                            const float* __restrict__ posp,
                                            float* __restrict__ pairloss) {
  __shared__ Shm s;
  const int t = threadIdx.x;
  phase3(s, samples, snorm, posp, pairloss, blockIdx.x, t, t & 63, t >> 6);
}

__global__ __launch_bounds__(64) void k_p4(const float* __restrict__ pairloss,
                                           float* __restrict__ out) {
  phase4(pairloss, out, threadIdx.x);
}

extern "C" void kernel_launch(void* const* d_in, const int* in_sizes, int n_in,
                              void* d_out, int out_size, void* d_ws, size_t ws_size,
                              hipStream_t stream) {
  const float* I  = (const float*)d_in[0];
  const float* g1 = (const float*)d_in[2];
  const float* g2 = (const float*)d_in[3];
  float* out = (float*)d_out;

  float* ws = (float*)d_ws;
  float* norms    = ws;                                   // 64*4096      = 262144
  float* partial  = ws + 262144;                          // 1024*512     = 524288
  float* samples  = partial + 524288;                     // 128*512      = 65536
  float* snorm    = samples + 65536;                      // 128
  float* posp     = snorm + 128;                          // 1 (+pad)
  float* pairloss = posp + 4;                             // 62 (+pad)

  // ---- try cooperative path, sized by the runtime's own occupancy math ----
  int dev = 0, coop = 0, ncu = 0, occ = 0;
  bool ok = (hipGetDevice(&dev) == hipSuccess);
  if (ok) hipDeviceGetAttribute(&coop, hipDeviceAttributeCooperativeLaunch, dev);
  if (ok) hipDeviceGetAttribute(&ncu, hipDeviceAttributeMultiprocessorCount, dev);
  if (ok && coop && ncu > 0) {
    if (hipOccupancyMaxActiveBlocksPerMultiprocessor(&occ, (const void*)k_all,
                                                     256, 0) != hipSuccess)
      occ = 0;
  }
  long maxb = (long)occ * (long)ncu;
  if (ok && coop && maxb >= D_EMB + 2) {
    int nblk = (int)(maxb < NCHUNK ? maxb : NCHUNK);
    void* args[] = { (void*)&I, (void*)&g1, (void*)&g2,
                     (void*)&partial, (void*)&norms, (void*)&samples,
                     (void*)&snorm, (void*)&posp, (void*)&pairloss, (void*)&out };
    if (hipLaunchCooperativeKernel((const void*)k_all, dim3(nblk), dim3(256),
                                   args, 0, stream) == hipSuccess)
      return;
  }

  // ---- fallback: known-good 4-kernel chain ----
  k_p1<<<NCHUNK,    256, 0, stream>>>(I, partial, norms);
  k_p2<<<D_EMB + 1, 256, 0, stream>>>(I, partial, norms, g1, g2, samples, snorm, posp);
  k_p3<<<P_PAIRS,   256, 0, stream>>>(samples, snorm, posp, pairloss);
  k_p4<<<1,          64, 0, stream>>>(pairloss, out);
}

// Round 5
// 312.042 us; speedup vs baseline: 1.2835x; 1.2835x over previous
//
#include <hip/hip_runtime.h>
#include <stdint.h>

#define D_EMB   64
#define N_ROWS  4096
#define DIM     512
#define KNEG    64
#define P_PAIRS 62
#define BPE     32                      // chunks per embedding in phase 1
#define RPB     (N_ROWS / BPE)          // 128 rows per chunk
#define NCHUNK  (D_EMB * BPE)           // 2048 chunks
#define EPSN    1e-8f
#define INV_T   10.0f

// ---------------- threefry-2x32-20 (matches JAX partitionable path) ---------
__device__ __forceinline__ uint32_t rotl32(uint32_t v, uint32_t r) {
  return (v << r) | (v >> (32u - r));
}

__device__ __forceinline__ void threefry(uint32_t k0, uint32_t k1,
                                         uint32_t c0, uint32_t c1,
                                         uint32_t& o0, uint32_t& o1) {
  uint32_t ks0 = k0, ks1 = k1, ks2 = k0 ^ k1 ^ 0x1BD11BDAu;
  uint32_t x0 = c0 + ks0, x1 = c1 + ks1;
#define RG(a,b,c,d) \
  x0 += x1; x1 = rotl32(x1,a); x1 ^= x0; \
  x0 += x1; x1 = rotl32(x1,b); x1 ^= x0; \
  x0 += x1; x1 = rotl32(x1,c); x1 ^= x0; \
  x0 += x1; x1 = rotl32(x1,d); x1 ^= x0;
  RG(13,15,26,6)   x0 += ks1; x1 += ks2 + 1u;
  RG(17,29,16,24)  x0 += ks2; x1 += ks0 + 2u;
  RG(13,15,26,6)   x0 += ks0; x1 += ks1 + 3u;
  RG(17,29,16,24)  x0 += ks1; x1 += ks2 + 4u;
  RG(13,15,26,6)   x0 += ks2; x1 += ks0 + 5u;
#undef RG
  o0 = x0; o1 = x1;
}

// ---------------- shared memory --------------------------------------------
struct Shm {
  float    lds[4 * DIM];      // 8 KB: phase-1 column transpose
  float    nlds[RPB];
  float    rA[4], rB[4], rC[4];
  int      wbi[4];
  int      flag;
  int      topidx[KNEG];
  uint32_t bits[126];
  uint32_t sk[2];
  int      sel[KNEG];
  float    simi[KNEG], simj[KNEG];
};

// ---------------- kernel 1: stream + per-embedding finalize -----------------
// grid: NCHUNK+1 blocks, 256 threads.
__global__ __launch_bounds__(256, 6) void k_p1p2(const float* __restrict__ I,
                                                 const float* __restrict__ g1,
                                                 const float* __restrict__ g2,
                                                 float* __restrict__ partial,
                                                 float* __restrict__ norms,
                                                 float* __restrict__ samples,
                                                 float* __restrict__ snorm,
                                                 float* __restrict__ posp,
                                                 int* __restrict__ cnt) {
  const int t = threadIdx.x, lane = t & 63, w = t >> 6;
  __shared__ Shm s;
  const int bid = blockIdx.x;

  if (bid == NCHUNK) {      // positive-pair scalar (independent of I)
    float x0 = g1[t], x1 = g1[256 + t], y0 = g2[t], y1 = g2[256 + t];
    float d = x0*y0 + x1*y1, sa = x0*x0 + x1*x1, sb = y0*y0 + y1*y1;
#pragma unroll
    for (int off = 32; off; off >>= 1) {
      d  += __shfl_xor(d, off);
      sa += __shfl_xor(sa, off);
      sb += __shfl_xor(sb, off);
    }
    if (lane == 0) { s.rA[w] = d; s.rB[w] = sa; s.rC[w] = sb; }
    __syncthreads();
    if (t == 0) {
      float dt = s.rA[0] + s.rA[1] + s.rA[2] + s.rA[3];
      float s1 = s.rB[0] + s.rB[1] + s.rB[2] + s.rB[3];
      float s2 = s.rC[0] + s.rC[1] + s.rC[2] + s.rC[3];
      posp[0] = dt / (fmaxf(sqrtf(s1), EPSN) * fmaxf(sqrtf(s2), EPSN)) * INV_T;
    }
    return;
  }

  // ===== phase 1: one 128-row chunk -> partial col-sums + row norms =====
  const int e = bid >> 5, b = bid & 31;
  const float4* base = reinterpret_cast<const float4*>(I) + (size_t)e * N_ROWS * (DIM / 4);
  const int nbase = b * RPB;
  float acc[8] = {0.f,0.f,0.f,0.f,0.f,0.f,0.f,0.f};
  for (int i = 0; i < RPB / 8; ++i) {          // 16 iters, 2 rows per wave
    const int na = nbase + i * 8 + w;
    const int nb = na + 4;
    const float4* ra = base + (size_t)na * (DIM / 4);
    const float4* rb = base + (size_t)nb * (DIM / 4);
    float4 A0 = ra[lane];
    float4 B0 = ra[lane + 64];
    float4 A1 = rb[lane];
    float4 B1 = rb[lane + 64];
    acc[0] += A0.x + A1.x; acc[1] += A0.y + A1.y;
    acc[2] += A0.z + A1.z; acc[3] += A0.w + A1.w;
    acc[4] += B0.x + B1.x; acc[5] += B0.y + B1.y;
    acc[6] += B0.z + B1.z; acc[7] += B0.w + B1.w;
    float sq0 = A0.x*A0.x + A0.y*A0.y + A0.z*A0.z + A0.w*A0.w
              + B0.x*B0.x + B0.y*B0.y + B0.z*B0.z + B0.w*B0.w;
    float sq1 = A1.x*A1.x + A1.y*A1.y + A1.z*A1.z + A1.w*A1.w
              + B1.x*B1.x + B1.y*B1.y + B1.z*B1.z + B1.w*B1.w;
#pragma unroll
    for (int off = 32; off; off >>= 1) {
      sq0 += __shfl_xor(sq0, off);
      sq1 += __shfl_xor(sq1, off);
    }
    if (lane == 0) {
      s.nlds[i * 8 + w]     = sqrtf(sq0);
      s.nlds[i * 8 + 4 + w] = sqrtf(sq1);
    }
  }
  const int p0 = 4 * lane;
#pragma unroll
  for (int q = 0; q < 4; ++q) {
    s.lds[w * DIM + p0 + q]       = acc[q];
    s.lds[w * DIM + 256 + p0 + q] = acc[4 + q];
  }
  __syncthreads();
  {
    float s0 = s.lds[t] + s.lds[DIM + t] + s.lds[2*DIM + t] + s.lds[3*DIM + t];
    float s1 = s.lds[256 + t] + s.lds[DIM + 256 + t] + s.lds[2*DIM + 256 + t] + s.lds[3*DIM + 256 + t];
    float* po = partial + (size_t)bid * DIM;
    po[t] = s0;
    po[256 + t] = s1;
    if (t < RPB) norms[e * N_ROWS + nbase + t] = s.nlds[t];
  }

  // ===== last-arriving block of this embedding runs phase 2 =====
  __syncthreads();
  if (t == 0) {
    int old = __hip_atomic_fetch_add(&cnt[e], 1, __ATOMIC_ACQ_REL,
                                     __HIP_MEMORY_SCOPE_AGENT);
    s.flag = (old == BPE - 1) ? 1 : 0;
  }
  __syncthreads();
  const int trig = s.flag;
  __syncthreads();
  if (!trig) return;
  __builtin_amdgcn_fence(__ATOMIC_ACQUIRE, "agent");

  // ---- top-64 of norms[e]; 16 candidates per thread in registers ----
  float v[16];
#pragma unroll
  for (int q = 0; q < 16; ++q) v[q] = norms[e * N_ROWS + q * 256 + t];
  float lmax = v[0]; int lidx = t;
#pragma unroll
  for (int q = 1; q < 16; ++q)
    if (v[q] > lmax) { lmax = v[q]; lidx = q * 256 + t; }

  for (int k = 0; k < KNEG; ++k) {
    float bv = lmax; int bi = lidx;
#pragma unroll
    for (int off = 32; off; off >>= 1) {
      float ov = __shfl_xor(bv, off);
      int   oi = __shfl_xor(bi, off);
      if (ov > bv || (ov == bv && oi < bi)) { bv = ov; bi = oi; }
    }
    if (lane == 0) { s.rA[w] = bv; s.wbi[w] = bi; }
    __syncthreads();
    float fv = s.rA[0]; int fi = s.wbi[0];
#pragma unroll
    for (int q = 1; q < 4; ++q)
      if (s.rA[q] > fv || (s.rA[q] == fv && s.wbi[q] < fi)) { fv = s.rA[q]; fi = s.wbi[q]; }
    if (t == (fi & 255)) {               // owner removes & rescans its 16
      v[fi >> 8] = -1e30f;
      lmax = v[0]; lidx = t;
#pragma unroll
      for (int q = 1; q < 16; ++q)
        if (v[q] > lmax) { lmax = v[q]; lidx = q * 256 + t; }
    }
    if (t == 0) s.topidx[k] = fi;
    __syncthreads();
  }

  // ---- fold partials -> sums ----
  float s0 = 0.f, s1 = 0.f;
  for (int b2 = 0; b2 < BPE; ++b2) {
    const float* pp = partial + (size_t)(e * BPE + b2) * DIM;
    s0 += pp[t];
    s1 += pp[256 + t];
  }
  // ---- gather top-64 rows, subtract ----
  const float* rbase = I + (size_t)e * N_ROWS * DIM;
  float a0 = 0.f, a1 = 0.f;
#pragma unroll 4
  for (int k = 0; k < KNEG; ++k) {
    const float* r = rbase + (size_t)s.topidx[k] * DIM;
    a0 += r[t];
    a1 += r[256 + t];
  }
  float sn0 = s0 - a0, sn1 = s1 - a1;

  float q1 = s0 * s0 + s1 * s1, q2 = sn0 * sn0 + sn1 * sn1;
#pragma unroll
  for (int off = 32; off; off >>= 1) {
    q1 += __shfl_xor(q1, off);
    q2 += __shfl_xor(q2, off);
  }
  if (lane == 0) { s.rA[w] = q1; s.rB[w] = q2; }
  __syncthreads();
  if (t == 0) {
    float n1 = s.rA[0] + s.rA[1] + s.rA[2] + s.rA[3];
    float n2 = s.rB[0] + s.rB[1] + s.rB[2] + s.rB[3];
    snorm[e]         = fmaxf(sqrtf(n1), EPSN);
    snorm[D_EMB + e] = fmaxf(sqrtf(n2), EPSN);
  }
  samples[(size_t)e * DIM + t]                 = s0;
  samples[(size_t)e * DIM + 256 + t]           = s1;
  samples[(size_t)(D_EMB + e) * DIM + t]       = sn0;
  samples[(size_t)(D_EMB + e) * DIM + 256 + t] = sn1;
}

// ---------------- kernel 2: pair losses + final sum -------------------------
// grid: P_PAIRS blocks, 256 threads
__global__ __launch_bounds__(256) void k_p3p4(const float* __restrict__ samples,
                                              const float* __restrict__ snorm,
                                              const float* __restrict__ posp,
                                              float* __restrict__ pairloss,
                                              int* __restrict__ cnt2,
                                              float* __restrict__ out) {
  const int p = blockIdx.x;
  const int t = threadIdx.x, lane = t & 63, w = t >> 6;
  __shared__ Shm s;

  if (t == 0) {
    uint32_t kh, kl, a, b;
    threefry(0u, 42u, 0u, (uint32_t)p, kh, kl);   // keys[p] = split(key(42),62)[p]
    threefry(kh, kl, 0u, 1u, a, b);               // subkey = split(keys[p])[1]
    s.sk[0] = a; s.sk[1] = b;
  }
  __syncthreads();
  if (t < 126) {
    uint32_t a, b;
    threefry(s.sk[0], s.sk[1], 0u, (uint32_t)t, a, b);
    s.bits[t] = a ^ b;                            // partitionable 32-bit path
  }
  __syncthreads();
  if (t < 126) {
    const uint32_t myb = s.bits[t];
    int rank = 0;
    for (int j = 0; j < 126; ++j) {
      const uint32_t bj = s.bits[j];
      rank += ((bj < myb) || (bj == myb && j < t)) ? 1 : 0;
    }
    if (rank < KNEG) {
      int vv = t + (t >= p ? 1 : 0);              // cand mapping: skip i=p
      vv += (vv >= p + 2 ? 1 : 0);                // then skip j=p+2
      s.sel[rank] = vv;
    }
  }
  __syncthreads();

  const float4* S = reinterpret_cast<const float4*>(samples);
  const float4 siA = S[p * 128 + lane],       siB = S[p * 128 + 64 + lane];
  const float4 sjA = S[(p + 2) * 128 + lane], sjB = S[(p + 2) * 128 + 64 + lane];
  const float ni = snorm[p], nj = snorm[p + 2];
  for (int k = w; k < KNEG; k += 4) {
    const int r = s.sel[k];
    const float4 vA = S[r * 128 + lane], vB = S[r * 128 + 64 + lane];
    float di = siA.x*vA.x + siA.y*vA.y + siA.z*vA.z + siA.w*vA.w
             + siB.x*vB.x + siB.y*vB.y + siB.z*vB.z + siB.w*vB.w;
    float dj = sjA.x*vA.x + sjA.y*vA.y + sjA.z*vA.z + sjA.w*vA.w
             + sjB.x*vB.x + sjB.y*vB.y + sjB.z*vB.z + sjB.w*vB.w;
#pragma unroll
    for (int off = 32; off; off >>= 1) {
      di += __shfl_xor(di, off);
      dj += __shfl_xor(dj, off);
    }
    if (lane == 0) {
      const float nr = snorm[r];
      s.simi[k] = di / (ni * nr) * INV_T;
      s.simj[k] = dj / (nj * nr) * INV_T;
    }
  }
  __syncthreads();
  if (t < KNEG) {
    const float xi = s.simi[t], xj = s.simj[t];
    float mi = xi, mj = xj;
#pragma unroll
    for (int off = 32; off; off >>= 1) {
      mi = fmaxf(mi, __shfl_xor(mi, off));
      mj = fmaxf(mj, __shfl_xor(mj, off));
    }
    float ei = expf(xi - mi), ej = expf(xj - mj);
#pragma unroll
    for (int off = 32; off; off >>= 1) {
      ei += __shfl_xor(ei, off);
      ej += __shfl_xor(ej, off);
    }
    if (t == 0) {
      const float pos = posp[0];
      const float lsei = mi + logf(ei), lsej = mj + logf(ej);
      const float li = fmaxf(pos, lsei) + log1pf(expf(-fabsf(pos - lsei))) - pos;
      const float lj = fmaxf(pos, lsej) + log1pf(expf(-fabsf(pos - lsej))) - pos;
      pairloss[p] = li + lj;
    }
  }
  __syncthreads();

  // ---- last-arriving pair block does the final sum ----
  if (t == 0) {
    int old = __hip_atomic_fetch_add(cnt2, 1, __ATOMIC_ACQ_REL,
                                     __HIP_MEMORY_SCOPE_AGENT);
    s.flag = (old == P_PAIRS - 1) ? 1 : 0;
  }
  __syncthreads();
  if (!s.flag) return;
  __builtin_amdgcn_fence(__ATOMIC_ACQUIRE, "agent");
  if (t < 64) {
    float vv = (t < P_PAIRS) ? pairloss[t] : 0.f;
#pragma unroll
    for (int off = 32; off; off >>= 1) vv += __shfl_xor(vv, off);
    if (t == 0) out[0] = vv;
  }
}

extern "C" void kernel_launch(void* const* d_in, const int* in_sizes, int n_in,
                              void* d_out, int out_size, void* d_ws, size_t ws_size,
                              hipStream_t stream) {
  const float* I  = (const float*)d_in[0];
  const float* g1 = (const float*)d_in[2];
  const float* g2 = (const float*)d_in[3];
  float* out = (float*)d_out;

  float* ws = (float*)d_ws;
  float* norms    = ws;                                   // 64*4096     = 262144
  float* partial  = ws + 262144;                          // 2048*512    = 1048576
  float* samples  = partial + 1048576;                    // 128*512     = 65536
  float* snorm    = samples + 65536;                      // 128
  float* posp     = snorm + 128;                          // 1 (+pad)
  float* pairloss = posp + 4;                             // 62 (+pad 64)
  int*   cnt      = (int*)(pairloss + 64);                // 64 ints
  int*   cnt2     = cnt + 64;                             // 1 int

  hipMemsetAsync(cnt, 0, 65 * sizeof(int), stream);       // re-runs each replay

  k_p1p2<<<NCHUNK + 1, 256, 0, stream>>>(I, g1, g2, partial, norms,
                                         samples, snorm, posp, cnt);
  k_p3p4<<<P_PAIRS,    256, 0, stream>>>(samples, snorm, posp, pairloss,
                                         cnt2, out);
}

// Round 6
// 215.285 us; speedup vs baseline: 1.8604x; 1.4494x over previous
//
#include <hip/hip_runtime.h>
#include <stdint.h>

#define D_EMB   64
#define N_ROWS  4096
#define DIM     512
#define KNEG    64
#define P_PAIRS 62
#define BPE     32                      // chunks per embedding in pass1
#define RPB     (N_ROWS / BPE)          // 128 rows per chunk
#define NCHUNK  (D_EMB * BPE)           // 2048 blocks
#define EPSN    1e-8f
#define INV_T   10.0f

// ---------------- threefry-2x32-20 (matches JAX partitionable path) ---------
__device__ __forceinline__ uint32_t rotl32(uint32_t v, uint32_t r) {
  return (v << r) | (v >> (32u - r));
}

__device__ __forceinline__ void threefry(uint32_t k0, uint32_t k1,
                                         uint32_t c0, uint32_t c1,
                                         uint32_t& o0, uint32_t& o1) {
  uint32_t ks0 = k0, ks1 = k1, ks2 = k0 ^ k1 ^ 0x1BD11BDAu;
  uint32_t x0 = c0 + ks0, x1 = c1 + ks1;
#define RG(a,b,c,d) \
  x0 += x1; x1 = rotl32(x1,a); x1 ^= x0; \
  x0 += x1; x1 = rotl32(x1,b); x1 ^= x0; \
  x0 += x1; x1 = rotl32(x1,c); x1 ^= x0; \
  x0 += x1; x1 = rotl32(x1,d); x1 ^= x0;
  RG(13,15,26,6)   x0 += ks1; x1 += ks2 + 1u;
  RG(17,29,16,24)  x0 += ks2; x1 += ks0 + 2u;
  RG(13,15,26,6)   x0 += ks0; x1 += ks1 + 3u;
  RG(17,29,16,24)  x0 += ks1; x1 += ks2 + 4u;
  RG(13,15,26,6)   x0 += ks2; x1 += ks0 + 5u;
#undef RG
  o0 = x0; o1 = x1;
}

// ---------------- pass 1: row norms + per-block partial sums ----------------
// grid: 2048 blocks, 256 threads, 8 blocks/CU resident. Depth-2 load pipeline.
__global__ __launch_bounds__(256, 8) void k_pass1(const float* __restrict__ I,
                                                  float* __restrict__ partial,
                                                  float* __restrict__ norms) {
  const int e = blockIdx.x >> 5, b = blockIdx.x & 31;
  const int t = threadIdx.x, lane = t & 63, w = t >> 6;
  const float4* base = reinterpret_cast<const float4*>(I) + (size_t)e * N_ROWS * (DIM / 4);
  const int nbase = b * RPB;
  __shared__ float lds[4 * DIM];
  __shared__ float nlds[RPB];
  float acc[8] = {0.f,0.f,0.f,0.f,0.f,0.f,0.f,0.f};

#define CONSUME(ii, Av, Bv)                                                   \
  {                                                                           \
    acc[0] += Av.x; acc[1] += Av.y; acc[2] += Av.z; acc[3] += Av.w;           \
    acc[4] += Bv.x; acc[5] += Bv.y; acc[6] += Bv.z; acc[7] += Bv.w;           \
    float sq = Av.x*Av.x + Av.y*Av.y + Av.z*Av.z + Av.w*Av.w                  \
             + Bv.x*Bv.x + Bv.y*Bv.y + Bv.z*Bv.z + Bv.w*Bv.w;                 \
    _Pragma("unroll")                                                         \
    for (int off = 32; off; off >>= 1) sq += __shfl_xor(sq, off);             \
    if (lane == 0) nlds[(ii) * 4 + w] = sqrtf(sq);                            \
  }

  // prologue: load row for iter 0
  const float4* r0 = base + (size_t)(nbase + w) * (DIM / 4);
  float4 A = r0[lane];
  float4 B = r0[lane + 64];
  for (int i = 0; i < RPB / 4 - 1; ++i) {
    const float4* rn = base + (size_t)(nbase + (i + 1) * 4 + w) * (DIM / 4);
    float4 An = rn[lane];           // issued before consuming current row:
    float4 Bn = rn[lane + 64];      // wait becomes vmcnt(2), reduce overlaps
    CONSUME(i, A, B);
    A = An; B = Bn;
  }
  CONSUME(RPB / 4 - 1, A, B);
#undef CONSUME

  const int p0 = 4 * lane;
#pragma unroll
  for (int q = 0; q < 4; ++q) {
    lds[w * DIM + p0 + q]       = acc[q];
    lds[w * DIM + 256 + p0 + q] = acc[4 + q];
  }
  __syncthreads();
  float s0 = lds[t] + lds[DIM + t] + lds[2*DIM + t] + lds[3*DIM + t];
  float s1 = lds[256 + t] + lds[DIM + 256 + t] + lds[2*DIM + 256 + t] + lds[3*DIM + 256 + t];
  float* po = partial + (size_t)blockIdx.x * DIM;
  po[t] = s0;
  po[256 + t] = s1;
  if (t < RPB) norms[e * N_ROWS + nbase + t] = nlds[t];
}

// ---------------- kernel 2: per-embedding top64 + fold + sumneg + norms -----
// grid: D_EMB+1 blocks, 512 threads. Block D_EMB computes the positive pair.
__global__ __launch_bounds__(512) void k_embed(const float* __restrict__ I,
                                               const float* __restrict__ partial,
                                               const float* __restrict__ norms,
                                               const float* __restrict__ g1,
                                               const float* __restrict__ g2,
                                               float* __restrict__ samples,
                                               float* __restrict__ snorm,
                                               float* __restrict__ posp) {
  const int e = blockIdx.x;
  const int t = threadIdx.x, lane = t & 63, w = t >> 6;
  __shared__ float rA[8], rB[8], rC[8];

  if (e == D_EMB) {
    float x = g1[t], y = g2[t];
    float d = x * y, sa = x * x, sb = y * y;
#pragma unroll
    for (int off = 32; off; off >>= 1) {
      d  += __shfl_xor(d, off);
      sa += __shfl_xor(sa, off);
      sb += __shfl_xor(sb, off);
    }
    if (lane == 0) { rA[w] = d; rB[w] = sa; rC[w] = sb; }
    __syncthreads();
    if (t == 0) {
      float dt = 0.f, s1 = 0.f, s2 = 0.f;
      for (int q = 0; q < 8; ++q) { dt += rA[q]; s1 += rB[q]; s2 += rC[q]; }
      posp[0] = dt / (fmaxf(sqrtf(s1), EPSN) * fmaxf(sqrtf(s2), EPSN)) * INV_T;
    }
    return;
  }

  // ---- top-64 of norms[e], candidates held in registers ----
  float v[8];
#pragma unroll
  for (int q = 0; q < 8; ++q) v[q] = norms[e * N_ROWS + q * DIM + t];
  float lmax = v[0]; int lidx = t;
#pragma unroll
  for (int q = 1; q < 8; ++q)
    if (v[q] > lmax) { lmax = v[q]; lidx = q * DIM + t; }

  __shared__ float wbv[8];
  __shared__ int   wbi[8];
  __shared__ int   topidx[KNEG];
  for (int k = 0; k < KNEG; ++k) {
    float bv = lmax; int bi = lidx;
#pragma unroll
    for (int off = 32; off; off >>= 1) {
      float ov = __shfl_xor(bv, off);
      int   oi = __shfl_xor(bi, off);
      if (ov > bv || (ov == bv && oi < bi)) { bv = ov; bi = oi; }
    }
    if (lane == 0) { wbv[w] = bv; wbi[w] = bi; }
    __syncthreads();
    float fv = wbv[0]; int fi = wbi[0];
#pragma unroll
    for (int q = 1; q < 8; ++q)
      if (wbv[q] > fv || (wbv[q] == fv && wbi[q] < fi)) { fv = wbv[q]; fi = wbi[q]; }
    if (t == (fi & (DIM - 1))) {          // owner thread removes & rescans 8
      v[fi >> 9] = -1e30f;
      lmax = v[0]; lidx = t;
#pragma unroll
      for (int q = 1; q < 8; ++q)
        if (v[q] > lmax) { lmax = v[q]; lidx = q * DIM + t; }
    }
    if (t == 0) topidx[k] = fi;
    __syncthreads();
  }

  // ---- fold partials -> sums ----
  float s = 0.f;
  for (int b2 = 0; b2 < BPE; ++b2)
    s += partial[(size_t)(e * BPE + b2) * DIM + t];

  // ---- gather top-64 rows, subtract ----
  const float* base = I + (size_t)e * N_ROWS * DIM;
  float a = 0.f;
#pragma unroll 4
  for (int k = 0; k < KNEG; ++k)
    a += base[(size_t)topidx[k] * DIM + t];
  float sn = s - a;

  // ---- norms of both sample rows ----
  float q1 = s * s, q2 = sn * sn;
#pragma unroll
  for (int off = 32; off; off >>= 1) {
    q1 += __shfl_xor(q1, off);
    q2 += __shfl_xor(q2, off);
  }
  if (lane == 0) { rA[w] = q1; rB[w] = q2; }
  __syncthreads();
  if (t == 0) {
    float n1 = 0.f, n2 = 0.f;
    for (int q = 0; q < 8; ++q) { n1 += rA[q]; n2 += rB[q]; }
    snorm[e]         = fmaxf(sqrtf(n1), EPSN);
    snorm[D_EMB + e] = fmaxf(sqrtf(n2), EPSN);
  }
  samples[(size_t)e * DIM + t]           = s;
  samples[(size_t)(D_EMB + e) * DIM + t] = sn;
}

// ---------------- kernel 3: select + sims + LSE + loss + final sum ----------
// grid: P_PAIRS blocks, 256 threads; last-arriving block sums pairloss.
__global__ __launch_bounds__(256) void k_p3p4(const float* __restrict__ samples,
                                              const float* __restrict__ snorm,
                                              const float* __restrict__ posp,
                                              float* __restrict__ pairloss,
                                              int* __restrict__ cnt2,
                                              float* __restrict__ out) {
  const int p = blockIdx.x;
  const int t = threadIdx.x, lane = t & 63, w = t >> 6;
  __shared__ uint32_t bits[126];
  __shared__ uint32_t sk[2];
  __shared__ int      sel[KNEG];
  __shared__ float    simi[KNEG], simj[KNEG];
  __shared__ int      flag;

  if (t == 0) {
    uint32_t kh, kl, a, b;
    threefry(0u, 42u, 0u, (uint32_t)p, kh, kl);   // keys[p] = split(key(42),62)[p]
    threefry(kh, kl, 0u, 1u, a, b);               // subkey = split(keys[p])[1]
    sk[0] = a; sk[1] = b;
  }
  __syncthreads();
  if (t < 126) {
    uint32_t a, b;
    threefry(sk[0], sk[1], 0u, (uint32_t)t, a, b);
    bits[t] = a ^ b;                              // partitionable 32-bit path
  }
  __syncthreads();
  if (t < 126) {
    const uint32_t myb = bits[t];
    int rank = 0;
    for (int j = 0; j < 126; ++j) {
      const uint32_t bj = bits[j];
      rank += ((bj < myb) || (bj == myb && j < t)) ? 1 : 0;
    }
    if (rank < KNEG) {
      int vv = t + (t >= p ? 1 : 0);              // cand mapping: skip i=p
      vv += (vv >= p + 2 ? 1 : 0);                // then skip j=p+2
      sel[rank] = vv;
    }
  }
  __syncthreads();

  const float4* S = reinterpret_cast<const float4*>(samples);
  const float4 siA = S[p * 128 + lane],       siB = S[p * 128 + 64 + lane];
  const float4 sjA = S[(p + 2) * 128 + lane], sjB = S[(p + 2) * 128 + 64 + lane];
  const float ni = snorm[p], nj = snorm[p + 2];
  for (int k = w; k < KNEG; k += 4) {
    const int r = sel[k];
    const float4 vA = S[r * 128 + lane], vB = S[r * 128 + 64 + lane];
    float di = siA.x*vA.x + siA.y*vA.y + siA.z*vA.z + siA.w*vA.w
             + siB.x*vB.x + siB.y*vB.y + siB.z*vB.z + siB.w*vB.w;
    float dj = sjA.x*vA.x + sjA.y*vA.y + sjA.z*vA.z + sjA.w*vA.w
             + sjB.x*vB.x + sjB.y*vB.y + sjB.z*vB.z + sjB.w*vB.w;
#pragma unroll
    for (int off = 32; off; off >>= 1) {
      di += __shfl_xor(di, off);
      dj += __shfl_xor(dj, off);
    }
    if (lane == 0) {
      const float nr = snorm[r];
      simi[k] = di / (ni * nr) * INV_T;
      simj[k] = dj / (nj * nr) * INV_T;
    }
  }
  __syncthreads();
  if (t < KNEG) {                                  // wave 0 only
    const float xi = simi[t], xj = simj[t];
    float mi = xi, mj = xj;
#pragma unroll
    for (int off = 32; off; off >>= 1) {
      mi = fmaxf(mi, __shfl_xor(mi, off));
      mj = fmaxf(mj, __shfl_xor(mj, off));
    }
    float ei = expf(xi - mi), ej = expf(xj - mj);
#pragma unroll
    for (int off = 32; off; off >>= 1) {
      ei += __shfl_xor(ei, off);
      ej += __shfl_xor(ej, off);
    }
    if (t == 0) {
      const float pos = posp[0];
      const float lsei = mi + logf(ei), lsej = mj + logf(ej);
      const float li = fmaxf(pos, lsei) + log1pf(expf(-fabsf(pos - lsei))) - pos;
      const float lj = fmaxf(pos, lsej) + log1pf(expf(-fabsf(pos - lsej))) - pos;
      pairloss[p] = li + lj;
    }
  }
  __syncthreads();

  // ---- last-arriving pair block does the final sum ----
  if (t == 0) {
    int old = __hip_atomic_fetch_add(cnt2, 1, __ATOMIC_ACQ_REL,
                                     __HIP_MEMORY_SCOPE_AGENT);
    flag = (old == P_PAIRS - 1) ? 1 : 0;
  }
  __syncthreads();
  const int trig = flag;
  __syncthreads();
  if (!trig) return;
  __builtin_amdgcn_fence(__ATOMIC_ACQUIRE, "agent");
  if (t < 64) {
    float vv = (t < P_PAIRS) ? pairloss[t] : 0.f;
#pragma unroll
    for (int off = 32; off; off >>= 1) vv += __shfl_xor(vv, off);
    if (t == 0) out[0] = vv;
  }
}

extern "C" void kernel_launch(void* const* d_in, const int* in_sizes, int n_in,
                              void* d_out, int out_size, void* d_ws, size_t ws_size,
                              hipStream_t stream) {
  const float* I  = (const float*)d_in[0];
  const float* g1 = (const float*)d_in[2];
  const float* g2 = (const float*)d_in[3];
  float* out = (float*)d_out;

  float* ws = (float*)d_ws;
  float* norms    = ws;                                   // 64*4096     = 262144
  float* partial  = ws + 262144;                          // 2048*512    = 1048576
  float* samples  = partial + 1048576;                    // 128*512     = 65536
  float* snorm    = samples + 65536;                      // 128
  float* posp     = snorm + 128;                          // 1 (+pad)
  float* pairloss = posp + 4;                             // 62 (+pad 64)
  int*   cnt2     = (int*)(pairloss + 64);                // 1 int

  hipMemsetAsync(cnt2, 0, sizeof(int), stream);           // re-zero each replay

  k_pass1<<<NCHUNK,    256, 0, stream>>>(I, partial, norms);
  k_embed<<<D_EMB + 1, 512, 0, stream>>>(I, partial, norms, g1, g2,
                                         samples, snorm, posp);
  k_p3p4 <<<P_PAIRS,   256, 0, stream>>>(samples, snorm, posp, pairloss,
                                         cnt2, out);
}